// Round 1
// baseline (278.311 us; speedup 1.0000x reference)
//
#include <hip/hip_runtime.h>
#include <cfloat>

#define N_NODES 10000
#define N_EDGES 320000
#define IN_F    512
#define F1      1024   // heads(4) * per-head channels(256)
#define OUT_F   128
#define NEG     0.2f
#define BUCKET  128    // fixed edge-slots per dst node (max degree ~58)

typedef __attribute__((ext_vector_type(8))) short bf16x8;
typedef __attribute__((ext_vector_type(4))) float f32x4;

__device__ __forceinline__ float lrelu(float v) { return fmaxf(v, NEG * v); }

// round-to-nearest-even fp32 -> bf16 bits
__device__ __forceinline__ unsigned short f2bf(float f) {
    unsigned u = __float_as_uint(f);
    u += 0x7fff + ((u >> 16) & 1);
    return (unsigned short)(u >> 16);
}
__device__ __forceinline__ float bf2f(unsigned short h) {
    return __uint_as_float(((unsigned)h) << 16);
}
// unpack 2 bf16 from one uint (little-endian: low half = even channel)
__device__ __forceinline__ void u2f2(unsigned u, float& e0, float& e1) {
    e0 = __uint_as_float(u << 16);
    e1 = __uint_as_float(u & 0xffff0000u);
}

// 16-lane (DPP row) all-reduce sum via rotate-and-add: row_ror 1,2,4,8.
// Pure VALU (~2cy/step) vs the 4-deep ds_swizzle chain (~30cy LDS pipe each).
__device__ __forceinline__ float rsum16(float x) {
    x += __int_as_float(__builtin_amdgcn_update_dpp(0, __float_as_int(x), 0x121, 0xF, 0xF, false));
    x += __int_as_float(__builtin_amdgcn_update_dpp(0, __float_as_int(x), 0x122, 0xF, 0xF, false));
    x += __int_as_float(__builtin_amdgcn_update_dpp(0, __float_as_int(x), 0x124, 0xF, 0xF, false));
    x += __int_as_float(__builtin_amdgcn_update_dpp(0, __float_as_int(x), 0x128, 0xF, 0xF, false));
    return x;
}

// async global->LDS, 16B per lane; LDS dest = wave-uniform base + lane*16
__device__ __forceinline__ void gld_lds16(const void* g, void* l) {
    __builtin_amdgcn_global_load_lds(
        (const __attribute__((address_space(1))) unsigned int*)g,
        (__attribute__((address_space(3))) unsigned int*)l, 16, 0, 0);
}

// ---------------- fused prologue: x->bf16 + bucket-scatter + weight transposes --
#define PB_X  2500
#define PB_S  3750
#define PB_W1 4774
#define PB_END 5030

__device__ __forceinline__ void wt_body(const float* __restrict__ Wa,
                                        const float* __restrict__ Wb,
                                        unsigned short* __restrict__ tbf,
                                        int K, int NS, int n0, int k0, int t,
                                        float (*tile)[33]) {
    int j = t & 31;
    const float* W = (n0 < NS) ? Wa : Wb;
    int nb = (n0 < NS) ? n0 : n0 - NS;
#pragma unroll
    for (int r = 0; r < 4; ++r) {
        int kl = (t >> 5) + r * 8;
        tile[kl][j] = W[(size_t)(k0 + kl) * NS + nb + j];
    }
    __syncthreads();
#pragma unroll
    for (int r = 0; r < 4; ++r) {
        int nl = (t >> 5) + r * 8;
        tbf[(size_t)(n0 + nl) * K + k0 + j] = f2bf(tile[j][nl]);
    }
}

__global__ __launch_bounds__(256) void k_prep(const float* __restrict__ x,
                                              unsigned short* __restrict__ xbf,
                                              const int* __restrict__ ei,
                                              int* __restrict__ cnt,
                                              int* __restrict__ esrc,
                                              const float* __restrict__ Wl1,
                                              const float* __restrict__ Wr1,
                                              unsigned short* __restrict__ w1bf,
                                              const float* __restrict__ Wl2,
                                              const float* __restrict__ Wr2,
                                              unsigned short* __restrict__ w2bf) {
    __shared__ float tile[32][33];
    int bid = blockIdx.x, t = threadIdx.x;
    if (bid < PB_X) {
        int i = bid * 2048 + t * 8;          // 8 floats per thread
        float4 v0 = *(const float4*)(x + i);
        float4 v1 = *(const float4*)(x + i + 4);
        ushort4 h0, h1;
        h0.x = f2bf(v0.x); h0.y = f2bf(v0.y); h0.z = f2bf(v0.z); h0.w = f2bf(v0.w);
        h1.x = f2bf(v1.x); h1.y = f2bf(v1.y); h1.z = f2bf(v1.z); h1.w = f2bf(v1.w);
        *(ushort4*)(xbf + i) = h0;
        *(ushort4*)(xbf + i + 4) = h1;
    } else if (bid < PB_S) {
        // one-pass CSR: bucket scatter + degree count
        int e = (bid - PB_X) * 256 + t;
        if (e < N_EDGES) {
            int d = ei[N_EDGES + e];
            int pos = atomicAdd(&cnt[d], 1);
            if (pos < BUCKET) esrc[(size_t)d * BUCKET + pos] = ei[e];
        }
    } else if (bid < PB_W1) {
        int local = bid - PB_S;
        wt_body(Wl1, Wr1, w1bf, IN_F, F1, (local & 63) * 32, (local >> 6) * 32, t, tile);
    } else {
        int local = bid - PB_W1;
        wt_body(Wl2, Wr2, w2bf, F1, OUT_F, (local & 7) * 32, (local >> 3) * 32, t, tile);
    }
}

// ---------------- bf16 MFMA GEMM, global_load_lds staging ----------------
template<int BM, int WR, int WC>
__global__ __launch_bounds__(256) void gemm_mfma(
        const unsigned short* __restrict__ A,
        const unsigned short* __restrict__ B,
        unsigned short* __restrict__ Cl, unsigned short* __restrict__ Cr,
        int M, int K, int NSPLIT) {
    constexpr int NI = BM / (16 * WR);
    constexpr int NJ = 128 / (16 * WC);
    __shared__ __align__(16) short As[BM * 32];
    __shared__ __align__(16) short Bs[128 * 32];
    int t = threadIdx.x;
    int lane = t & 63, w = t >> 6;
    int row0 = blockIdx.y * BM;
    int n0 = blockIdx.x * 128;
    int wr0 = (w / WC) * (NI * 16);
    int wc0 = (w % WC) * (NJ * 16);
    int q = lane >> 4, md = lane & 15;
    int srow = t >> 2;
    int skoff = (t & 3) * 8;

    f32x4 acc[NI][NJ];
#pragma unroll
    for (int i = 0; i < NI; ++i)
#pragma unroll
        for (int j = 0; j < NJ; ++j)
#pragma unroll
            for (int r = 0; r < 4; ++r) acc[i][j][r] = 0.f;

    for (int k0 = 0; k0 < K; k0 += 32) {
        __syncthreads();
#pragma unroll
        for (int is = 0; is < BM / 64; ++is) {
            int gr = row0 + is * 64 + srow;
            if (gr < M)
                gld_lds16(A + (size_t)gr * K + k0 + skoff,
                          &As[(is * 64 + (t >> 6) * 16) * 32]);
        }
#pragma unroll
        for (int is = 0; is < 2; ++is) {
            int gn = n0 + is * 64 + srow;
            gld_lds16(B + (size_t)gn * K + k0 + skoff,
                      &Bs[(is * 64 + (t >> 6) * 16) * 32]);
        }
        __syncthreads();

        bf16x8 av[NI], bv[NJ];
#pragma unroll
        for (int i = 0; i < NI; ++i)
            av[i] = *(const bf16x8*)&As[(wr0 + i * 16 + md) * 32 + q * 8];
#pragma unroll
        for (int j = 0; j < NJ; ++j)
            bv[j] = *(const bf16x8*)&Bs[(wc0 + j * 16 + md) * 32 + q * 8];
#pragma unroll
        for (int i = 0; i < NI; ++i)
#pragma unroll
            for (int j = 0; j < NJ; ++j)
                acc[i][j] = __builtin_amdgcn_mfma_f32_16x16x32_bf16(av[i], bv[j], acc[i][j], 0, 0, 0);
    }

    // epilogue: C/D layout col=lane&15, row=(lane>>4)*4+reg (m89-verified)
#pragma unroll
    for (int i = 0; i < NI; ++i)
#pragma unroll
        for (int j = 0; j < NJ; ++j) {
            int col = n0 + wc0 + j * 16 + md;
            unsigned short* C = (col < NSPLIT) ? Cl : Cr;
            int cc = (col < NSPLIT) ? col : col - NSPLIT;
#pragma unroll
            for (int r = 0; r < 4; ++r) {
                int grow = row0 + wr0 + i * 16 + q * 4 + r;
                if (grow < M) C[(size_t)grow * NSPLIT + cc] = f2bf(acc[i][j][r]);
            }
        }
}

// ---------------- P precompute: P[n][h] = att_h . xl[n,h,:] ----------------
// Enables the per-edge score factorization s = 0.6(P_j + Q_i) + 0.4*att.|xl_j+xr_i|
// (lrelu(u) = 0.6u + 0.4|u| exactly, for slope 0.2). One wave per node.
__global__ __launch_bounds__(256) void k_pq1(const unsigned short* __restrict__ xlbf,
                                             const float* __restrict__ att,
                                             float* __restrict__ P) {
    int t = threadIdx.x;
    int w = t >> 6, lane = t & 63;
    int nd = blockIdx.x * 4 + w;
    int head = lane >> 4, sub = lane & 15;
    int ch = head * 256 + sub * 16;
    const uint4* px = (const uint4*)(xlbf + (size_t)nd * F1 + ch);
    uint4 xa = px[0], xb = px[1];
    const float4* pa = (const float4*)(att + ch);
    float4 a0 = pa[0], a1 = pa[1], a2 = pa[2], a3 = pa[3];
    float4 c0, c1, c2, c3;
    u2f2(xa.x, c0.x, c0.y); u2f2(xa.y, c0.z, c0.w);
    u2f2(xa.z, c1.x, c1.y); u2f2(xa.w, c1.z, c1.w);
    u2f2(xb.x, c2.x, c2.y); u2f2(xb.y, c2.z, c2.w);
    u2f2(xb.z, c3.x, c3.y); u2f2(xb.w, c3.z, c3.w);
    float s0 = a0.x * c0.x;
    s0 = fmaf(a0.y, c0.y, s0); s0 = fmaf(a0.z, c0.z, s0); s0 = fmaf(a0.w, c0.w, s0);
    float s1 = a1.x * c1.x;
    s1 = fmaf(a1.y, c1.y, s1); s1 = fmaf(a1.z, c1.z, s1); s1 = fmaf(a1.w, c1.w, s1);
    float s2 = a2.x * c2.x;
    s2 = fmaf(a2.y, c2.y, s2); s2 = fmaf(a2.z, c2.z, s2); s2 = fmaf(a2.w, c2.w, s2);
    float s3 = a3.x * c3.x;
    s3 = fmaf(a3.y, c3.y, s3); s3 = fmaf(a3.z, c3.z, s3); s3 = fmaf(a3.w, c3.w, s3);
    float s = rsum16((s0 + s1) + (s2 + s3));
    if (sub == 0) P[nd * 4 + head] = s;
}

// ---------------- conv1 fused edge phase ----------------
// One wave per node (no LDS merge, no __syncthreads). Score via the abs
// factorization: s = 0.6*(P[src]+Q) + 0.4*sum a*|xl_j+xr_i| — 2 VALU/channel
// instead of 4 (abs folds into the fma input modifier). 16-lane reduce via
// DPP rotate-add. No-max softmax (|s| bounded; clamp +-60 insurance).
// Prefetch depth 2 on the gathered xl rows to cover L3-hit latency.
__global__ __launch_bounds__(256) void k_fused1(const unsigned short* __restrict__ xlbf,
                                                const unsigned short* __restrict__ xrbf,
                                                const int* __restrict__ cnt,
                                                const int* __restrict__ esrc,
                                                const float* __restrict__ att,
                                                const float* __restrict__ Pbuf,
                                                const float* __restrict__ bias,
                                                unsigned short* __restrict__ hb) {
    int t = threadIdx.x;
    int w = t >> 6, lane = t & 63;
    int nd = blockIdx.x * 4 + w;
    int head = lane >> 4, sub = lane & 15;
    int ch = head * 256 + sub * 16;

    float4 r0, r1, r2, r3;
    {
        const uint4* prx = (const uint4*)(xrbf + (size_t)nd * F1 + ch);
        uint4 xa = prx[0], xb = prx[1];
        u2f2(xa.x, r0.x, r0.y); u2f2(xa.y, r0.z, r0.w);
        u2f2(xa.z, r1.x, r1.y); u2f2(xa.w, r1.z, r1.w);
        u2f2(xb.x, r2.x, r2.y); u2f2(xb.y, r2.z, r2.w);
        u2f2(xb.z, r3.x, r3.y); u2f2(xb.w, r3.z, r3.w);
    }
    const float4* pa = (const float4*)(att + ch);
    float4 a0 = pa[0], a1 = pa[1], a2 = pa[2], a3 = pa[3];

    // Q = att . xr for this node/head (once per node)
    float qd = a0.x * r0.x;
    qd = fmaf(a0.y, r0.y, qd); qd = fmaf(a0.z, r0.z, qd); qd = fmaf(a0.w, r0.w, qd);
    qd = fmaf(a1.x, r1.x, qd); qd = fmaf(a1.y, r1.y, qd);
    qd = fmaf(a1.z, r1.z, qd); qd = fmaf(a1.w, r1.w, qd);
    qd = fmaf(a2.x, r2.x, qd); qd = fmaf(a2.y, r2.y, qd);
    qd = fmaf(a2.z, r2.z, qd); qd = fmaf(a2.w, r2.w, qd);
    qd = fmaf(a3.x, r3.x, qd); qd = fmaf(a3.y, r3.y, qd);
    qd = fmaf(a3.z, r3.z, qd); qd = fmaf(a3.w, r3.w, qd);
    float Qk = 0.6f * rsum16(qd);          // 0.6*Q, folded for the per-edge fma

    int deg = min(cnt[nd], BUCKET);
    int p0 = nd * BUCKET;
    int p1 = p0 + deg;

    float l = 0.f;
    float4 acc0 = make_float4(0.f, 0.f, 0.f, 0.f);
    float4 acc1 = acc0, acc2 = acc0, acc3 = acc0;

    uint4 A0 = {}, B0 = {}, A1 = {}, B1 = {};
    float Pv0 = 0.f, Pv1 = 0.f;
    if (p0 < p1) {
        int sn = esrc[p0];
        const uint4* pv = (const uint4*)(xlbf + (size_t)sn * F1 + ch);
        A0 = pv[0]; B0 = pv[1]; Pv0 = Pbuf[sn * 4 + head];
    }
    if (p0 + 1 < p1) {
        int sn = esrc[p0 + 1];
        const uint4* pv = (const uint4*)(xlbf + (size_t)sn * F1 + ch);
        A1 = pv[0]; B1 = pv[1]; Pv1 = Pbuf[sn * 4 + head];
    }
    for (int p = p0; p < p1; ++p) {
        uint4 ca = A0, cb = B0;
        float Pv = Pv0;
        A0 = A1; B0 = B1; Pv0 = Pv1;
        if (p + 2 < p1) {
            int sn = esrc[p + 2];
            const uint4* pv = (const uint4*)(xlbf + (size_t)sn * F1 + ch);
            A1 = pv[0]; B1 = pv[1]; Pv1 = Pbuf[sn * 4 + head];
        }
        float4 c0, c1, c2, c3;
        u2f2(ca.x, c0.x, c0.y); u2f2(ca.y, c0.z, c0.w);
        u2f2(ca.z, c1.x, c1.y); u2f2(ca.w, c1.z, c1.w);
        u2f2(cb.x, c2.x, c2.y); u2f2(cb.y, c2.z, c2.w);
        u2f2(cb.z, c3.x, c3.y); u2f2(cb.w, c3.z, c3.w);
        float s0 = a0.x * fabsf(c0.x + r0.x);
        s0 = fmaf(a0.y, fabsf(c0.y + r0.y), s0);
        s0 = fmaf(a0.z, fabsf(c0.z + r0.z), s0);
        s0 = fmaf(a0.w, fabsf(c0.w + r0.w), s0);
        float s1 = a1.x * fabsf(c1.x + r1.x);
        s1 = fmaf(a1.y, fabsf(c1.y + r1.y), s1);
        s1 = fmaf(a1.z, fabsf(c1.z + r1.z), s1);
        s1 = fmaf(a1.w, fabsf(c1.w + r1.w), s1);
        float s2 = a2.x * fabsf(c2.x + r2.x);
        s2 = fmaf(a2.y, fabsf(c2.y + r2.y), s2);
        s2 = fmaf(a2.z, fabsf(c2.z + r2.z), s2);
        s2 = fmaf(a2.w, fabsf(c2.w + r2.w), s2);
        float s3 = a3.x * fabsf(c3.x + r3.x);
        s3 = fmaf(a3.y, fabsf(c3.y + r3.y), s3);
        s3 = fmaf(a3.z, fabsf(c3.z + r3.z), s3);
        s3 = fmaf(a3.w, fabsf(c3.w + r3.w), s3);
        float sab = rsum16((s0 + s1) + (s2 + s3));
        float sarg = fmaf(0.6f, Pv, Qk);           // 0.6*(P+Q)
        sarg = fmaf(0.4f, sab, sarg);              // + 0.4*att.|u|  == att.lrelu(u)
        sarg = fminf(fmaxf(sarg, -60.f), 60.f);    // insurance; data keeps |s| < ~6
        float al = __expf(sarg);
        l += al;
        acc0.x = fmaf(al, c0.x, acc0.x);
        acc0.y = fmaf(al, c0.y, acc0.y);
        acc0.z = fmaf(al, c0.z, acc0.z);
        acc0.w = fmaf(al, c0.w, acc0.w);
        acc1.x = fmaf(al, c1.x, acc1.x);
        acc1.y = fmaf(al, c1.y, acc1.y);
        acc1.z = fmaf(al, c1.z, acc1.z);
        acc1.w = fmaf(al, c1.w, acc1.w);
        acc2.x = fmaf(al, c2.x, acc2.x);
        acc2.y = fmaf(al, c2.y, acc2.y);
        acc2.z = fmaf(al, c2.z, acc2.z);
        acc2.w = fmaf(al, c2.w, acc2.w);
        acc3.x = fmaf(al, c3.x, acc3.x);
        acc3.y = fmaf(al, c3.y, acc3.y);
        acc3.z = fmaf(al, c3.z, acc3.z);
        acc3.w = fmaf(al, c3.w, acc3.w);
    }

    // l is identical across each 16-lane group (sab/sarg uniform post-reduce)
    float invL = (l > 0.f) ? 1.f / l : 0.f;
    const float4* pb = (const float4*)(bias + ch);
    size_t base = (size_t)nd * F1 + ch;
    float4 aa[4] = {acc0, acc1, acc2, acc3};
#pragma unroll
    for (int j = 0; j < 4; ++j) {
        float4 b4 = pb[j];
        ushort4 hv;
        hv.x = f2bf(fmaxf(fmaf(aa[j].x, invL, b4.x), 0.f));
        hv.y = f2bf(fmaxf(fmaf(aa[j].y, invL, b4.y), 0.f));
        hv.z = f2bf(fmaxf(fmaf(aa[j].z, invL, b4.z), 0.f));
        hv.w = f2bf(fmaxf(fmaf(aa[j].w, invL, b4.w), 0.f));
        *(ushort4*)(hb + base + j * 4) = hv;
    }
}

// ---------------- conv2 fused edge phase: no-max softmax, 4 edge-slots --------
__global__ __launch_bounds__(256) void k_fused2(const unsigned short* __restrict__ xlbf,
                                                const unsigned short* __restrict__ xrbf,
                                                const int* __restrict__ cnt,
                                                const int* __restrict__ esrc,
                                                const float* __restrict__ att,
                                                const float* __restrict__ bias,
                                                float* __restrict__ out) {
    int t = threadIdx.x;
    int w = t >> 6, lane = t & 63;
    int nd = blockIdx.x * 4 + w;
    int g = lane >> 4, sub = lane & 15;
    int ch = sub * 8;

    __shared__ float slx2[4][4];                // [node][slot]
    __shared__ float sacc2[4][4][132];          // [node][slot][ch], +4 pad

    float r[8], a[8];
    {
        uint4 u = *(const uint4*)(xrbf + (size_t)nd * OUT_F + ch);
        u2f2(u.x, r[0], r[1]); u2f2(u.y, r[2], r[3]);
        u2f2(u.z, r[4], r[5]); u2f2(u.w, r[6], r[7]);
        float4 q0 = *(const float4*)(att + ch);
        float4 q1 = *(const float4*)(att + ch + 4);
        a[0] = q0.x; a[1] = q0.y; a[2] = q0.z; a[3] = q0.w;
        a[4] = q1.x; a[5] = q1.y; a[6] = q1.z; a[7] = q1.w;
    }
    int deg = min(cnt[nd], BUCKET);
    int p0 = nd * BUCKET;
    int p1 = p0 + deg;

    float l = 0.f;
    float acc[8] = {};
    uint4 cur, nxt;
    {
        int p = p0 + g;
        if (p < p1)     cur = *(const uint4*)(xlbf + (size_t)esrc[p] * OUT_F + ch);
        if (p + 4 < p1) nxt = *(const uint4*)(xlbf + (size_t)esrc[p + 4] * OUT_F + ch);
    }
    for (int p = p0 + g; p < p1; p += 4) {
        uint4 c = cur;
        cur = nxt;
        if (p + 8 < p1) nxt = *(const uint4*)(xlbf + (size_t)esrc[p + 8] * OUT_F + ch);
        float v[8];
        u2f2(c.x, v[0], v[1]); u2f2(c.y, v[2], v[3]);
        u2f2(c.z, v[4], v[5]); u2f2(c.w, v[6], v[7]);
        float sx = a[0] * lrelu(v[0] + r[0]);
        sx = fmaf(a[1], lrelu(v[1] + r[1]), sx);
        sx = fmaf(a[2], lrelu(v[2] + r[2]), sx);
        sx = fmaf(a[3], lrelu(v[3] + r[3]), sx);
        float sy = a[4] * lrelu(v[4] + r[4]);
        sy = fmaf(a[5], lrelu(v[5] + r[5]), sy);
        sy = fmaf(a[6], lrelu(v[6] + r[6]), sy);
        sy = fmaf(a[7], lrelu(v[7] + r[7]), sy);
        float s = rsum16(sx + sy);
        s = fminf(fmaxf(s, -60.f), 60.f);
        float al = __expf(s);
        l += al;
#pragma unroll
        for (int k = 0; k < 8; ++k) acc[k] = fmaf(al, v[k], acc[k]);
    }

    // 4-slot merge: plain sums
    if (sub == 0) slx2[w][g] = l;
    float4 v0 = make_float4(acc[0], acc[1], acc[2], acc[3]);
    float4 v1 = make_float4(acc[4], acc[5], acc[6], acc[7]);
    *(float4*)&sacc2[w][g][ch] = v0;
    *(float4*)&sacc2[w][g][ch + 4] = v1;
    __syncthreads();
    float L = slx2[w][0] + slx2[w][1] + slx2[w][2] + slx2[w][3];
    float invL = (L > 0.f) ? 1.f / L : 0.f;
    int c2 = lane * 2;
    float o0 = sacc2[w][0][c2] + sacc2[w][1][c2] + sacc2[w][2][c2] + sacc2[w][3][c2];
    float o1 = sacc2[w][0][c2 + 1] + sacc2[w][1][c2 + 1] + sacc2[w][2][c2 + 1] + sacc2[w][3][c2 + 1];
    float2 bf = *(const float2*)(bias + c2);
    float2 o;
    o.x = fmaf(o0, invL, bf.x);
    o.y = fmaf(o1, invL, bf.y);
    *(float2*)(out + (size_t)nd * OUT_F + c2) = o;
}

extern "C" void kernel_launch(void* const* d_in, const int* in_sizes, int n_in,
                              void* d_out, int out_size, void* d_ws, size_t ws_size,
                              hipStream_t stream) {
    const float* x    = (const float*)d_in[0];
    const int*   ei   = (const int*)d_in[1];
    const float* Wl1  = (const float*)d_in[2];
    const float* Wr1  = (const float*)d_in[3];
    const float* att1 = (const float*)d_in[4];
    const float* b1   = (const float*)d_in[5];
    const float* Wl2  = (const float*)d_in[6];
    const float* Wr2  = (const float*)d_in[7];
    const float* att2 = (const float*)d_in[8];
    const float* b2   = (const float*)d_in[9];
    float* out = (float*)d_out;

    unsigned short* us = (unsigned short*)d_ws;
    unsigned short* xl1bf = us;                          // [N,1024] bf16
    unsigned short* xr1bf = xl1bf + (size_t)N_NODES * F1;// [N,1024] bf16
    unsigned short* xl2bf = xr1bf + (size_t)N_NODES * F1;// [N,128]  bf16
    unsigned short* xr2bf = xl2bf + (size_t)N_NODES * OUT_F;
    unsigned short* hb   = xr2bf + (size_t)N_NODES * OUT_F; // [N,1024] bf16
    unsigned short* xbf  = hb + (size_t)N_NODES * F1;    // [N,512] bf16
    unsigned short* w1bf = xbf + (size_t)N_NODES * IN_F; // [2048,512] bf16
    unsigned short* w2bf = w1bf + (size_t)2048 * IN_F;   // [256,1024] bf16
    int* cnt   = (int*)(w2bf + (size_t)256 * F1);        // [N]
    int* esrc  = cnt + (N_NODES + 16);                   // [N*BUCKET]
    float* Pbuf = (float*)(esrc + (size_t)N_NODES * BUCKET); // [N,4] f32

    hipMemsetAsync(cnt, 0, sizeof(int) * N_NODES, stream);
    // fused prologue: x -> bf16 + one-pass bucket CSR + weight transposes
    k_prep<<<PB_END, 256, 0, stream>>>(x, xbf, ei, cnt, esrc,
                                       Wl1, Wr1, w1bf,
                                       Wl2, Wr2, w2bf);

    // conv1 projections: [10000,512] @ [512,2048] -> xl1|xr1 (both bf16)
    gemm_mfma<128, 2, 2><<<dim3(16, (N_NODES + 127) / 128), 256, 0, stream>>>(
        xbf, w1bf, xl1bf, xr1bf, N_NODES, IN_F, F1);

    // P[n][h] = att_h . xl1[n,h,:]  (for the factorized GATv2 score)
    k_pq1<<<N_NODES / 4, 256, 0, stream>>>(xl1bf, att1, Pbuf);

    // conv1 fused scores + softmax + aggregate (+bias+ReLU) -> hb (bf16)
    k_fused1<<<N_NODES / 4, 256, 0, stream>>>(xl1bf, xr1bf, cnt, esrc, att1, Pbuf, b1, hb);

    // conv2 projections: [10000,1024] @ [1024,256] -> xl2|xr2 (both bf16)
    gemm_mfma<64, 1, 4><<<dim3(2, (N_NODES + 63) / 64), 256, 0, stream>>>(
        hb, w2bf, xl2bf, xr2bf, N_NODES, F1, OUT_F);

    // conv2 fused scores + softmax + aggregate (+bias)
    k_fused2<<<N_NODES / 4, 256, 0, stream>>>(xl2bf, xr2bf, cnt, esrc, att2, b2, out);
}

// Round 2
// 276.845 us; speedup vs baseline: 1.0053x; 1.0053x over previous
//
#include <hip/hip_runtime.h>
#include <cfloat>

#define N_NODES 10000
#define N_EDGES 320000
#define IN_F    512
#define F1      1024   // heads(4) * per-head channels(256)
#define OUT_F   128
#define NEG     0.2f
#define BUCKET  128    // fixed edge-slots per dst node (max degree ~58)

typedef __attribute__((ext_vector_type(8))) short bf16x8;
typedef __attribute__((ext_vector_type(4))) float f32x4;

__device__ __forceinline__ float lrelu(float v) { return fmaxf(v, NEG * v); }

// round-to-nearest-even fp32 -> bf16 bits
__device__ __forceinline__ unsigned short f2bf(float f) {
    unsigned u = __float_as_uint(f);
    u += 0x7fff + ((u >> 16) & 1);
    return (unsigned short)(u >> 16);
}
__device__ __forceinline__ float bf2f(unsigned short h) {
    return __uint_as_float(((unsigned)h) << 16);
}
// unpack 2 bf16 from one uint (little-endian: low half = even channel)
__device__ __forceinline__ void u2f2(unsigned u, float& e0, float& e1) {
    e0 = __uint_as_float(u << 16);
    e1 = __uint_as_float(u & 0xffff0000u);
}

// 16-lane (DPP row) all-reduce sum via rotate-and-add: row_ror 1,2,4,8.
// Pure VALU (~2cy/step) vs a 4-deep ds_swizzle chain (~30cy LDS pipe each).
__device__ __forceinline__ float rsum16(float x) {
    x += __int_as_float(__builtin_amdgcn_update_dpp(0, __float_as_int(x), 0x121, 0xF, 0xF, false));
    x += __int_as_float(__builtin_amdgcn_update_dpp(0, __float_as_int(x), 0x122, 0xF, 0xF, false));
    x += __int_as_float(__builtin_amdgcn_update_dpp(0, __float_as_int(x), 0x124, 0xF, 0xF, false));
    x += __int_as_float(__builtin_amdgcn_update_dpp(0, __float_as_int(x), 0x128, 0xF, 0xF, false));
    return x;
}

// async global->LDS, 16B per lane; LDS dest = wave-uniform base + lane*16
__device__ __forceinline__ void gld_lds16(const void* g, void* l) {
    __builtin_amdgcn_global_load_lds(
        (const __attribute__((address_space(1))) unsigned int*)g,
        (__attribute__((address_space(3))) unsigned int*)l, 16, 0, 0);
}

// ---------------- fused prologue: x->bf16 + bucket-scatter + weight transposes --
#define PB_X  2500
#define PB_S  3750
#define PB_W1 4774
#define PB_END 5030

__device__ __forceinline__ void wt_body(const float* __restrict__ Wa,
                                        const float* __restrict__ Wb,
                                        unsigned short* __restrict__ tbf,
                                        int K, int NS, int n0, int k0, int t,
                                        float (*tile)[33]) {
    int j = t & 31;
    const float* W = (n0 < NS) ? Wa : Wb;
    int nb = (n0 < NS) ? n0 : n0 - NS;
#pragma unroll
    for (int r = 0; r < 4; ++r) {
        int kl = (t >> 5) + r * 8;
        tile[kl][j] = W[(size_t)(k0 + kl) * NS + nb + j];
    }
    __syncthreads();
#pragma unroll
    for (int r = 0; r < 4; ++r) {
        int nl = (t >> 5) + r * 8;
        tbf[(size_t)(n0 + nl) * K + k0 + j] = f2bf(tile[j][nl]);
    }
}

__global__ __launch_bounds__(256) void k_prep(const float* __restrict__ x,
                                              unsigned short* __restrict__ xbf,
                                              const int* __restrict__ ei,
                                              int* __restrict__ cnt,
                                              int* __restrict__ esrc,
                                              const float* __restrict__ Wl1,
                                              const float* __restrict__ Wr1,
                                              unsigned short* __restrict__ w1bf,
                                              const float* __restrict__ Wl2,
                                              const float* __restrict__ Wr2,
                                              unsigned short* __restrict__ w2bf) {
    __shared__ float tile[32][33];
    int bid = blockIdx.x, t = threadIdx.x;
    if (bid < PB_X) {
        int i = bid * 2048 + t * 8;          // 8 floats per thread
        float4 v0 = *(const float4*)(x + i);
        float4 v1 = *(const float4*)(x + i + 4);
        ushort4 h0, h1;
        h0.x = f2bf(v0.x); h0.y = f2bf(v0.y); h0.z = f2bf(v0.z); h0.w = f2bf(v0.w);
        h1.x = f2bf(v1.x); h1.y = f2bf(v1.y); h1.z = f2bf(v1.z); h1.w = f2bf(v1.w);
        *(ushort4*)(xbf + i) = h0;
        *(ushort4*)(xbf + i + 4) = h1;
    } else if (bid < PB_S) {
        // one-pass CSR: bucket scatter + degree count
        int e = (bid - PB_X) * 256 + t;
        if (e < N_EDGES) {
            int d = ei[N_EDGES + e];
            int pos = atomicAdd(&cnt[d], 1);
            if (pos < BUCKET) esrc[(size_t)d * BUCKET + pos] = ei[e];
        }
    } else if (bid < PB_W1) {
        int local = bid - PB_S;
        wt_body(Wl1, Wr1, w1bf, IN_F, F1, (local & 63) * 32, (local >> 6) * 32, t, tile);
    } else {
        int local = bid - PB_W1;
        wt_body(Wl2, Wr2, w2bf, F1, OUT_F, (local & 7) * 32, (local >> 3) * 32, t, tile);
    }
}

// ---------------- bf16 MFMA GEMM, global_load_lds staging ----------------
template<int BM, int WR, int WC>
__global__ __launch_bounds__(256) void gemm_mfma(
        const unsigned short* __restrict__ A,
        const unsigned short* __restrict__ B,
        unsigned short* __restrict__ Cl, unsigned short* __restrict__ Cr,
        int M, int K, int NSPLIT) {
    constexpr int NI = BM / (16 * WR);
    constexpr int NJ = 128 / (16 * WC);
    __shared__ __align__(16) short As[BM * 32];
    __shared__ __align__(16) short Bs[128 * 32];
    int t = threadIdx.x;
    int lane = t & 63, w = t >> 6;
    int row0 = blockIdx.y * BM;
    int n0 = blockIdx.x * 128;
    int wr0 = (w / WC) * (NI * 16);
    int wc0 = (w % WC) * (NJ * 16);
    int q = lane >> 4, md = lane & 15;
    int srow = t >> 2;
    int skoff = (t & 3) * 8;

    f32x4 acc[NI][NJ];
#pragma unroll
    for (int i = 0; i < NI; ++i)
#pragma unroll
        for (int j = 0; j < NJ; ++j)
#pragma unroll
            for (int r = 0; r < 4; ++r) acc[i][j][r] = 0.f;

    for (int k0 = 0; k0 < K; k0 += 32) {
        __syncthreads();
#pragma unroll
        for (int is = 0; is < BM / 64; ++is) {
            int gr = row0 + is * 64 + srow;
            if (gr < M)
                gld_lds16(A + (size_t)gr * K + k0 + skoff,
                          &As[(is * 64 + (t >> 6) * 16) * 32]);
        }
#pragma unroll
        for (int is = 0; is < 2; ++is) {
            int gn = n0 + is * 64 + srow;
            gld_lds16(B + (size_t)gn * K + k0 + skoff,
                      &Bs[(is * 64 + (t >> 6) * 16) * 32]);
        }
        __syncthreads();

        bf16x8 av[NI], bv[NJ];
#pragma unroll
        for (int i = 0; i < NI; ++i)
            av[i] = *(const bf16x8*)&As[(wr0 + i * 16 + md) * 32 + q * 8];
#pragma unroll
        for (int j = 0; j < NJ; ++j)
            bv[j] = *(const bf16x8*)&Bs[(wc0 + j * 16 + md) * 32 + q * 8];
#pragma unroll
        for (int i = 0; i < NI; ++i)
#pragma unroll
            for (int j = 0; j < NJ; ++j)
                acc[i][j] = __builtin_amdgcn_mfma_f32_16x16x32_bf16(av[i], bv[j], acc[i][j], 0, 0, 0);
    }

    // epilogue: C/D layout col=lane&15, row=(lane>>4)*4+reg (m89-verified)
#pragma unroll
    for (int i = 0; i < NI; ++i)
#pragma unroll
        for (int j = 0; j < NJ; ++j) {
            int col = n0 + wc0 + j * 16 + md;
            unsigned short* C = (col < NSPLIT) ? Cl : Cr;
            int cc = (col < NSPLIT) ? col : col - NSPLIT;
#pragma unroll
            for (int r = 0; r < 4; ++r) {
                int grow = row0 + wr0 + i * 16 + q * 4 + r;
                if (grow < M) C[(size_t)grow * NSPLIT + cc] = f2bf(acc[i][j][r]);
            }
        }
}

// ---------------- P precompute: P[n][h] = att_h . xl[n,h,:] ----------------
// Enables the per-edge score factorization s = 0.6(P_j + Q_i) + 0.4*att.|xl_j+xr_i|
// (lrelu(u) = 0.6u + 0.4|u| exactly, for slope 0.2). One wave per node.
__global__ __launch_bounds__(256) void k_pq1(const unsigned short* __restrict__ xlbf,
                                             const float* __restrict__ att,
                                             float* __restrict__ P) {
    int t = threadIdx.x;
    int w = t >> 6, lane = t & 63;
    int nd = blockIdx.x * 4 + w;
    int head = lane >> 4, sub = lane & 15;
    int ch = head * 256 + sub * 16;
    const uint4* px = (const uint4*)(xlbf + (size_t)nd * F1 + ch);
    uint4 xa = px[0], xb = px[1];
    const float4* pa = (const float4*)(att + ch);
    float4 a0 = pa[0], a1 = pa[1], a2 = pa[2], a3 = pa[3];
    float4 c0, c1, c2, c3;
    u2f2(xa.x, c0.x, c0.y); u2f2(xa.y, c0.z, c0.w);
    u2f2(xa.z, c1.x, c1.y); u2f2(xa.w, c1.z, c1.w);
    u2f2(xb.x, c2.x, c2.y); u2f2(xb.y, c2.z, c2.w);
    u2f2(xb.z, c3.x, c3.y); u2f2(xb.w, c3.z, c3.w);
    float s0 = a0.x * c0.x;
    s0 = fmaf(a0.y, c0.y, s0); s0 = fmaf(a0.z, c0.z, s0); s0 = fmaf(a0.w, c0.w, s0);
    float s1 = a1.x * c1.x;
    s1 = fmaf(a1.y, c1.y, s1); s1 = fmaf(a1.z, c1.z, s1); s1 = fmaf(a1.w, c1.w, s1);
    float s2 = a2.x * c2.x;
    s2 = fmaf(a2.y, c2.y, s2); s2 = fmaf(a2.z, c2.z, s2); s2 = fmaf(a2.w, c2.w, s2);
    float s3 = a3.x * c3.x;
    s3 = fmaf(a3.y, c3.y, s3); s3 = fmaf(a3.z, c3.z, s3); s3 = fmaf(a3.w, c3.w, s3);
    float s = rsum16((s0 + s1) + (s2 + s3));
    if (sub == 0) P[nd * 4 + head] = s;
}

// ---------------- conv1 fused edge phase ----------------
// Gather-BW bound (round-1 lesson): throughput scales with in-flight loads, so
// maximize TLP: 4 waves per node (1 node/block), each wave takes deg/4 edges
// (~8) with depth-2 prefetch -> ~40000 waves, ~2048 blocks resident.
// Score stays factorized: s = 0.6*(P[src]+Q) + 0.4*sum a*|xl_j+xr_i|
// (lrelu(u)=0.6u+0.4|u| exact for slope 0.2); abs folds into fma modifier.
// 16-lane reduce via DPP rotate-add. No-max softmax -> 4-way merge is plain sums.
__global__ __launch_bounds__(256) void k_fused1(const unsigned short* __restrict__ xlbf,
                                                const unsigned short* __restrict__ xrbf,
                                                const int* __restrict__ cnt,
                                                const int* __restrict__ esrc,
                                                const float* __restrict__ att,
                                                const float* __restrict__ Pbuf,
                                                const float* __restrict__ bias,
                                                unsigned short* __restrict__ hb) {
    int t = threadIdx.x;
    int w = t >> 6, lane = t & 63;
    int nd = blockIdx.x;
    int head = lane >> 4, sub = lane & 15;
    int ch = head * 256 + sub * 16;

    __shared__ float slx[4][4];              // [wave][head] partial l
    __shared__ float4 sacc[3][4][64];        // waves 1..3 partial acc [w-1][frag][lane]

    float4 r0, r1, r2, r3;
    {
        const uint4* prx = (const uint4*)(xrbf + (size_t)nd * F1 + ch);
        uint4 xa = prx[0], xb = prx[1];
        u2f2(xa.x, r0.x, r0.y); u2f2(xa.y, r0.z, r0.w);
        u2f2(xa.z, r1.x, r1.y); u2f2(xa.w, r1.z, r1.w);
        u2f2(xb.x, r2.x, r2.y); u2f2(xb.y, r2.z, r2.w);
        u2f2(xb.z, r3.x, r3.y); u2f2(xb.w, r3.z, r3.w);
    }
    const float4* pa = (const float4*)(att + ch);
    float4 a0 = pa[0], a1 = pa[1], a2 = pa[2], a3 = pa[3];

    // Q = att . xr for this node/head (once per wave; redundant across waves, cheap)
    float qd = a0.x * r0.x;
    qd = fmaf(a0.y, r0.y, qd); qd = fmaf(a0.z, r0.z, qd); qd = fmaf(a0.w, r0.w, qd);
    qd = fmaf(a1.x, r1.x, qd); qd = fmaf(a1.y, r1.y, qd);
    qd = fmaf(a1.z, r1.z, qd); qd = fmaf(a1.w, r1.w, qd);
    qd = fmaf(a2.x, r2.x, qd); qd = fmaf(a2.y, r2.y, qd);
    qd = fmaf(a2.z, r2.z, qd); qd = fmaf(a2.w, r2.w, qd);
    qd = fmaf(a3.x, r3.x, qd); qd = fmaf(a3.y, r3.y, qd);
    qd = fmaf(a3.z, r3.z, qd); qd = fmaf(a3.w, r3.w, qd);
    float Qk = 0.6f * rsum16(qd);          // 0.6*Q, folded for the per-edge fma

    int deg = min(cnt[nd], BUCKET);
    int p0 = nd * BUCKET;
    int per = (deg + 3) >> 2;              // edges per wave (chunked)
    int pa_ = p0 + min(w * per, deg);
    int pb_ = p0 + min((w + 1) * per, deg);

    float l = 0.f;
    float4 acc0 = make_float4(0.f, 0.f, 0.f, 0.f);
    float4 acc1 = acc0, acc2 = acc0, acc3 = acc0;

    uint4 A0 = {}, B0 = {}, A1 = {}, B1 = {};
    float Pv0 = 0.f, Pv1 = 0.f;
    if (pa_ < pb_) {
        int sn = esrc[pa_];
        const uint4* pv = (const uint4*)(xlbf + (size_t)sn * F1 + ch);
        A0 = pv[0]; B0 = pv[1]; Pv0 = Pbuf[sn * 4 + head];
    }
    if (pa_ + 1 < pb_) {
        int sn = esrc[pa_ + 1];
        const uint4* pv = (const uint4*)(xlbf + (size_t)sn * F1 + ch);
        A1 = pv[0]; B1 = pv[1]; Pv1 = Pbuf[sn * 4 + head];
    }
    for (int p = pa_; p < pb_; ++p) {
        uint4 ca = A0, cb = B0;
        float Pv = Pv0;
        A0 = A1; B0 = B1; Pv0 = Pv1;
        if (p + 2 < pb_) {
            int sn = esrc[p + 2];
            const uint4* pv = (const uint4*)(xlbf + (size_t)sn * F1 + ch);
            A1 = pv[0]; B1 = pv[1]; Pv1 = Pbuf[sn * 4 + head];
        }
        float4 c0, c1, c2, c3;
        u2f2(ca.x, c0.x, c0.y); u2f2(ca.y, c0.z, c0.w);
        u2f2(ca.z, c1.x, c1.y); u2f2(ca.w, c1.z, c1.w);
        u2f2(cb.x, c2.x, c2.y); u2f2(cb.y, c2.z, c2.w);
        u2f2(cb.z, c3.x, c3.y); u2f2(cb.w, c3.z, c3.w);
        float s0 = a0.x * fabsf(c0.x + r0.x);
        s0 = fmaf(a0.y, fabsf(c0.y + r0.y), s0);
        s0 = fmaf(a0.z, fabsf(c0.z + r0.z), s0);
        s0 = fmaf(a0.w, fabsf(c0.w + r0.w), s0);
        float s1 = a1.x * fabsf(c1.x + r1.x);
        s1 = fmaf(a1.y, fabsf(c1.y + r1.y), s1);
        s1 = fmaf(a1.z, fabsf(c1.z + r1.z), s1);
        s1 = fmaf(a1.w, fabsf(c1.w + r1.w), s1);
        float s2 = a2.x * fabsf(c2.x + r2.x);
        s2 = fmaf(a2.y, fabsf(c2.y + r2.y), s2);
        s2 = fmaf(a2.z, fabsf(c2.z + r2.z), s2);
        s2 = fmaf(a2.w, fabsf(c2.w + r2.w), s2);
        float s3 = a3.x * fabsf(c3.x + r3.x);
        s3 = fmaf(a3.y, fabsf(c3.y + r3.y), s3);
        s3 = fmaf(a3.z, fabsf(c3.z + r3.z), s3);
        s3 = fmaf(a3.w, fabsf(c3.w + r3.w), s3);
        float sab = rsum16((s0 + s1) + (s2 + s3));
        float sarg = fmaf(0.6f, Pv, Qk);           // 0.6*(P+Q)
        sarg = fmaf(0.4f, sab, sarg);              // + 0.4*att.|u|  == att.lrelu(u)
        sarg = fminf(fmaxf(sarg, -60.f), 60.f);    // insurance; data keeps |s| < ~6
        float al = __expf(sarg);
        l += al;
        acc0.x = fmaf(al, c0.x, acc0.x);
        acc0.y = fmaf(al, c0.y, acc0.y);
        acc0.z = fmaf(al, c0.z, acc0.z);
        acc0.w = fmaf(al, c0.w, acc0.w);
        acc1.x = fmaf(al, c1.x, acc1.x);
        acc1.y = fmaf(al, c1.y, acc1.y);
        acc1.z = fmaf(al, c1.z, acc1.z);
        acc1.w = fmaf(al, c1.w, acc1.w);
        acc2.x = fmaf(al, c2.x, acc2.x);
        acc2.y = fmaf(al, c2.y, acc2.y);
        acc2.z = fmaf(al, c2.z, acc2.z);
        acc2.w = fmaf(al, c2.w, acc2.w);
        acc3.x = fmaf(al, c3.x, acc3.x);
        acc3.y = fmaf(al, c3.y, acc3.y);
        acc3.z = fmaf(al, c3.z, acc3.z);
        acc3.w = fmaf(al, c3.w, acc3.w);
    }

    // 4-way merge: plain sums (no max reconciliation needed)
    if (sub == 0) slx[w][head] = l;
    if (w) {
        sacc[w - 1][0][lane] = acc0;
        sacc[w - 1][1][lane] = acc1;
        sacc[w - 1][2][lane] = acc2;
        sacc[w - 1][3][lane] = acc3;
    }
    __syncthreads();
    if (w == 0) {
        float L = slx[0][head] + slx[1][head] + slx[2][head] + slx[3][head];
        float invL = (L > 0.f) ? 1.f / L : 0.f;
        const float4* pb = (const float4*)(bias + ch);
        size_t base = (size_t)nd * F1 + ch;
        float4 aa[4] = {acc0, acc1, acc2, acc3};
#pragma unroll
        for (int j = 0; j < 4; ++j) {
            float4 q1 = sacc[0][j][lane];
            float4 q2 = sacc[1][j][lane];
            float4 q3 = sacc[2][j][lane];
            float4 b4 = pb[j];
            float sx = aa[j].x + q1.x + q2.x + q3.x;
            float sy = aa[j].y + q1.y + q2.y + q3.y;
            float sz = aa[j].z + q1.z + q2.z + q3.z;
            float sw = aa[j].w + q1.w + q2.w + q3.w;
            ushort4 hv;
            hv.x = f2bf(fmaxf(fmaf(sx, invL, b4.x), 0.f));
            hv.y = f2bf(fmaxf(fmaf(sy, invL, b4.y), 0.f));
            hv.z = f2bf(fmaxf(fmaf(sz, invL, b4.z), 0.f));
            hv.w = f2bf(fmaxf(fmaf(sw, invL, b4.w), 0.f));
            *(ushort4*)(hb + base + j * 4) = hv;
        }
    }
}

// ---------------- conv2 fused edge phase: no-max softmax, 4 edge-slots --------
__global__ __launch_bounds__(256) void k_fused2(const unsigned short* __restrict__ xlbf,
                                                const unsigned short* __restrict__ xrbf,
                                                const int* __restrict__ cnt,
                                                const int* __restrict__ esrc,
                                                const float* __restrict__ att,
                                                const float* __restrict__ bias,
                                                float* __restrict__ out) {
    int t = threadIdx.x;
    int w = t >> 6, lane = t & 63;
    int nd = blockIdx.x * 4 + w;
    int g = lane >> 4, sub = lane & 15;
    int ch = sub * 8;

    __shared__ float slx2[4][4];                // [node][slot]
    __shared__ float sacc2[4][4][132];          // [node][slot][ch], +4 pad

    float r[8], a[8];
    {
        uint4 u = *(const uint4*)(xrbf + (size_t)nd * OUT_F + ch);
        u2f2(u.x, r[0], r[1]); u2f2(u.y, r[2], r[3]);
        u2f2(u.z, r[4], r[5]); u2f2(u.w, r[6], r[7]);
        float4 q0 = *(const float4*)(att + ch);
        float4 q1 = *(const float4*)(att + ch + 4);
        a[0] = q0.x; a[1] = q0.y; a[2] = q0.z; a[3] = q0.w;
        a[4] = q1.x; a[5] = q1.y; a[6] = q1.z; a[7] = q1.w;
    }
    int deg = min(cnt[nd], BUCKET);
    int p0 = nd * BUCKET;
    int p1 = p0 + deg;

    float l = 0.f;
    float acc[8] = {};
    uint4 cur, nxt;
    {
        int p = p0 + g;
        if (p < p1)     cur = *(const uint4*)(xlbf + (size_t)esrc[p] * OUT_F + ch);
        if (p + 4 < p1) nxt = *(const uint4*)(xlbf + (size_t)esrc[p + 4] * OUT_F + ch);
    }
    for (int p = p0 + g; p < p1; p += 4) {
        uint4 c = cur;
        cur = nxt;
        if (p + 8 < p1) nxt = *(const uint4*)(xlbf + (size_t)esrc[p + 8] * OUT_F + ch);
        float v[8];
        u2f2(c.x, v[0], v[1]); u2f2(c.y, v[2], v[3]);
        u2f2(c.z, v[4], v[5]); u2f2(c.w, v[6], v[7]);
        float sx = a[0] * lrelu(v[0] + r[0]);
        sx = fmaf(a[1], lrelu(v[1] + r[1]), sx);
        sx = fmaf(a[2], lrelu(v[2] + r[2]), sx);
        sx = fmaf(a[3], lrelu(v[3] + r[3]), sx);
        float sy = a[4] * lrelu(v[4] + r[4]);
        sy = fmaf(a[5], lrelu(v[5] + r[5]), sy);
        sy = fmaf(a[6], lrelu(v[6] + r[6]), sy);
        sy = fmaf(a[7], lrelu(v[7] + r[7]), sy);
        float s = rsum16(sx + sy);
        s = fminf(fmaxf(s, -60.f), 60.f);
        float al = __expf(s);
        l += al;
#pragma unroll
        for (int k = 0; k < 8; ++k) acc[k] = fmaf(al, v[k], acc[k]);
    }

    // 4-slot merge: plain sums
    if (sub == 0) slx2[w][g] = l;
    float4 v0 = make_float4(acc[0], acc[1], acc[2], acc[3]);
    float4 v1 = make_float4(acc[4], acc[5], acc[6], acc[7]);
    *(float4*)&sacc2[w][g][ch] = v0;
    *(float4*)&sacc2[w][g][ch + 4] = v1;
    __syncthreads();
    float L = slx2[w][0] + slx2[w][1] + slx2[w][2] + slx2[w][3];
    float invL = (L > 0.f) ? 1.f / L : 0.f;
    int c2 = lane * 2;
    float o0 = sacc2[w][0][c2] + sacc2[w][1][c2] + sacc2[w][2][c2] + sacc2[w][3][c2];
    float o1 = sacc2[w][0][c2 + 1] + sacc2[w][1][c2 + 1] + sacc2[w][2][c2 + 1] + sacc2[w][3][c2 + 1];
    float2 bf = *(const float2*)(bias + c2);
    float2 o;
    o.x = fmaf(o0, invL, bf.x);
    o.y = fmaf(o1, invL, bf.y);
    *(float2*)(out + (size_t)nd * OUT_F + c2) = o;
}

extern "C" void kernel_launch(void* const* d_in, const int* in_sizes, int n_in,
                              void* d_out, int out_size, void* d_ws, size_t ws_size,
                              hipStream_t stream) {
    const float* x    = (const float*)d_in[0];
    const int*   ei   = (const int*)d_in[1];
    const float* Wl1  = (const float*)d_in[2];
    const float* Wr1  = (const float*)d_in[3];
    const float* att1 = (const float*)d_in[4];
    const float* b1   = (const float*)d_in[5];
    const float* Wl2  = (const float*)d_in[6];
    const float* Wr2  = (const float*)d_in[7];
    const float* att2 = (const float*)d_in[8];
    const float* b2   = (const float*)d_in[9];
    float* out = (float*)d_out;

    unsigned short* us = (unsigned short*)d_ws;
    unsigned short* xl1bf = us;                          // [N,1024] bf16
    unsigned short* xr1bf = xl1bf + (size_t)N_NODES * F1;// [N,1024] bf16
    unsigned short* xl2bf = xr1bf + (size_t)N_NODES * F1;// [N,128]  bf16
    unsigned short* xr2bf = xl2bf + (size_t)N_NODES * OUT_F;
    unsigned short* hb   = xr2bf + (size_t)N_NODES * OUT_F; // [N,1024] bf16
    unsigned short* xbf  = hb + (size_t)N_NODES * F1;    // [N,512] bf16
    unsigned short* w1bf = xbf + (size_t)N_NODES * IN_F; // [2048,512] bf16
    unsigned short* w2bf = w1bf + (size_t)2048 * IN_F;   // [256,1024] bf16
    int* cnt   = (int*)(w2bf + (size_t)256 * F1);        // [N]
    int* esrc  = cnt + (N_NODES + 16);                   // [N*BUCKET]
    float* Pbuf = (float*)(esrc + (size_t)N_NODES * BUCKET); // [N,4] f32

    hipMemsetAsync(cnt, 0, sizeof(int) * N_NODES, stream);
    // fused prologue: x -> bf16 + one-pass bucket CSR + weight transposes
    k_prep<<<PB_END, 256, 0, stream>>>(x, xbf, ei, cnt, esrc,
                                       Wl1, Wr1, w1bf,
                                       Wl2, Wr2, w2bf);

    // conv1 projections: [10000,512] @ [512,2048] -> xl1|xr1 (both bf16)
    gemm_mfma<128, 2, 2><<<dim3(16, (N_NODES + 127) / 128), 256, 0, stream>>>(
        xbf, w1bf, xl1bf, xr1bf, N_NODES, IN_F, F1);

    // P[n][h] = att_h . xl1[n,h,:]  (for the factorized GATv2 score)
    k_pq1<<<N_NODES / 4, 256, 0, stream>>>(xl1bf, att1, Pbuf);

    // conv1 fused scores + softmax + aggregate (+bias+ReLU) -> hb (bf16)
    // 4 waves per node: gather throughput scales with in-flight loads
    k_fused1<<<N_NODES, 256, 0, stream>>>(xl1bf, xr1bf, cnt, esrc, att1, Pbuf, b1, hb);

    // conv2 projections: [10000,1024] @ [1024,256] -> xl2|xr2 (both bf16)
    gemm_mfma<64, 1, 4><<<dim3(2, (N_NODES + 63) / 64), 256, 0, stream>>>(
        hb, w2bf, xl2bf, xr2bf, N_NODES, F1, OUT_F);

    // conv2 fused scores + softmax + aggregate (+bias)
    k_fused2<<<N_NODES / 4, 256, 0, stream>>>(xl2bf, xr2bf, cnt, esrc, att2, b2, out);
}